// Round 7
// baseline (804.666 us; speedup 1.0000x reference)
//
#include <hip/hip_runtime.h>
#include <hip/hip_bf16.h>

#define NTOK 1024
#define HDIM 2880
#define IDIM 2880
#define NEXP 8
#define BK 32
#define NSTEP 90  // HDIM/BK

typedef __attribute__((ext_vector_type(4))) float fx4;
typedef __attribute__((ext_vector_type(8))) short sx8;
typedef __attribute__((ext_vector_type(8))) unsigned short usx8;

typedef const __attribute__((address_space(1))) void* gas_p;
typedef __attribute__((address_space(3))) void* las_p;

__device__ __forceinline__ unsigned short f2bf(float f) {
  __hip_bfloat16 b = __float2bfloat16(f);
  return __builtin_bit_cast(unsigned short, b);
}
__device__ __forceinline__ usx8 cvt8(fx4 a, fx4 b) {
  usx8 u = {f2bf(a.x), f2bf(a.y), f2bf(a.z), f2bf(a.w),
            f2bf(b.x), f2bf(b.y), f2bf(b.z), f2bf(b.w)};
  return u;
}

#define MFMA16(a, b, c) __builtin_amdgcn_mfma_f32_16x16x32_bf16(a, b, c, 0, 0, 0)

__global__ __launch_bounds__(256) void init_out_k(const float* __restrict__ x,
                                                  float* __restrict__ out) {
  int i = blockIdx.x * 256 + threadIdx.x;
  ((fx4*)out)[i] = ((const fx4*)x)[i];
}

__global__ __launch_bounds__(256) void rms_router_k(
    const float* __restrict__ x, const float* __restrict__ norm_w,
    const float* __restrict__ gate_w, const float* __restrict__ gate_b,
    unsigned short* __restrict__ t_bf, int* __restrict__ cnt,
    int* __restrict__ tok, float* __restrict__ wgt) {
  const int n = blockIdx.x;
  const int tid = threadIdx.x;
  const int wid = tid >> 6, lane = tid & 63;
  const float* xr = x + (size_t)n * HDIM;

  float ss = 0.f;
  for (int h = tid; h < HDIM; h += 256) { float v = xr[h]; ss += v * v; }
  #pragma unroll
  for (int o = 32; o > 0; o >>= 1) ss += __shfl_down(ss, o);
  __shared__ float sred[4];
  if (lane == 0) sred[wid] = ss;
  __syncthreads();
  const float rstd =
      rsqrtf((sred[0] + sred[1] + sred[2] + sred[3]) * (1.0f / HDIM) + 1e-5f);

  float p[NEXP];
  #pragma unroll
  for (int e = 0; e < NEXP; e++) p[e] = 0.f;
  for (int h = tid; h < HDIM; h += 256) {
    float xv = xr[h] * norm_w[h];
    t_bf[(size_t)n * HDIM + h] = f2bf(xv * rstd);
    #pragma unroll
    for (int e = 0; e < NEXP; e++) p[e] += xv * gate_w[e * HDIM + h];
  }
  __shared__ float pls[4][NEXP];
  #pragma unroll
  for (int e = 0; e < NEXP; e++) {
    float v = p[e];
    #pragma unroll
    for (int o = 32; o > 0; o >>= 1) v += __shfl_down(v, o);
    if (lane == 0) pls[wid][e] = v;
  }
  __syncthreads();
  if (tid == 0) {
    float lg[NEXP];
    #pragma unroll
    for (int e = 0; e < NEXP; e++)
      lg[e] = (pls[0][e] + pls[1][e] + pls[2][e] + pls[3][e]) * rstd + gate_b[e];
    unsigned used = 0;
    float val[4];
    int idx[4];
    for (int k = 0; k < 4; k++) {
      float best = -1e30f;
      int bi = 0;
      for (int e = 0; e < NEXP; e++)
        if (!((used >> e) & 1u) && lg[e] > best) { best = lg[e]; bi = e; }
      used |= 1u << bi;
      val[k] = best;
      idx[k] = bi;
    }
    float sum = 0.f, w[4];
    for (int k = 0; k < 4; k++) { w[k] = expf(val[k] - val[0]); sum += w[k]; }
    for (int k = 0; k < 4; k++) {
      int e = idx[k];
      int slot = atomicAdd(&cnt[e], 1);
      tok[e * NTOK + slot] = n;
      wgt[e * NTOK + slot] = w[k] / sum;
    }
  }
}

// GEMM1: BM=128 x (32 G + 32 L), BK=32, 4 waves (2m x 2n), dbuf 24KB LDS,
// 5 blocks/CU. Twin row-tiles decoded to the same XCD (h = 64*(u>>3)+8*z+(u&7)).
__global__ __launch_bounds__(256, 5) void gemm1_k(
    const unsigned short* __restrict__ t_bf,
    const float* __restrict__ w_gate_up, const float* __restrict__ b_gate_up,
    const int* __restrict__ cnt, const int* __restrict__ tok,
    unsigned short* __restrict__ act_bf) {
  const int h = blockIdx.x;
  const int zl = (h >> 3) & 7;
  const int u = ((h >> 6) << 3) | (h & 7);  // u in [0,720)
  const int e = u / 90;
  const int c0 = (u % 90) * 32;
  const int m0 = zl * 128;
  const int ce = cnt[e];
  if (m0 >= ce) return;

  const int tid = threadIdx.x, lane = tid & 63, wid = tid >> 6;
  const int fr = lane & 15, fq = lane >> 4;
  const int wm = wid >> 1, wn = wid & 1;

  __shared__ __align__(16) unsigned short Ash[2][128 * BK];  // 2 x 8KB
  __shared__ __align__(16) unsigned short Bsh[2][64 * BK];   // 2 x 4KB

  const fx4 FZ = {0.f, 0.f, 0.f, 0.f};
  fx4 accG[4], accL[4];
  #pragma unroll
  for (int m = 0; m < 4; m++) { accG[m] = FZ; accL[m] = FZ; }

  // A gather: 2 gload_lds per wave, 16 rows each; source chunk pre-swizzled
  // so linear LDS write lands chunk^(row&3)^((row>>2)&3)-swizzled.
  const int srcc = ((lane & 3) ^ ((lane >> 2) & 3) ^ ((lane >> 4) & 3)) * 8;
  const unsigned short* gA[2];
  #pragma unroll
  for (int j = 0; j < 2; ++j) {
    int R = m0 + wid * 32 + j * 16 + (lane >> 2);
    int rc = R < ce ? R : ce - 1;
    gA[j] = t_bf + (size_t)tok[e * NTOK + rc] * HDIM + srcc;
  }
  // B: 64 rows (32 G + 32 L) x 32 floats; thread: row tid>>2, floats [(tid&3)*8,+8)
  const int br = tid >> 2, bs = tid & 3;
  const int wrow = br < 32 ? (c0 + br) : (IDIM + c0 + (br - 32));
  const float* srcB = w_gate_up + (size_t)e * (2 * IDIM) * HDIM +
                      (size_t)wrow * HDIM + bs * 8;
  const int bwo = br * BK + ((bs ^ (br & 3) ^ ((br >> 2) & 3)) * 8);

  const int rdc = (fq ^ (fr & 3) ^ ((fr >> 2) & 3)) * 8;
  int ao[4];
  #pragma unroll
  for (int m = 0; m < 4; m++) ao[m] = (wm * 64 + m * 16 + fr) * BK + rdc;
  const int bGo = (wn * 16 + fr) * BK + rdc;
  const int bLo = (32 + wn * 16 + fr) * BK + rdc;

  #define G1_STAGE(buf, kt)                                                    \
    {                                                                          \
      const int ko = ((kt) < NSTEP ? (kt) : 0) * BK;                           \
      __builtin_amdgcn_global_load_lds((gas_p)(gA[0] + ko),                    \
                                       (las_p)&Ash[buf][(wid * 32) * BK], 16,  \
                                       0, 0);                                  \
      __builtin_amdgcn_global_load_lds(                                        \
          (gas_p)(gA[1] + ko), (las_p)&Ash[buf][(wid * 32 + 16) * BK], 16, 0,  \
          0);                                                                  \
      fx4 v0 = *(const fx4*)(srcB + ko);                                       \
      fx4 v1 = *(const fx4*)(srcB + ko + 4);                                   \
      *(usx8*)&Bsh[buf][bwo] = cvt8(v0, v1);                                   \
    }
  #define G1_COMP(buf)                                                         \
    {                                                                          \
      sx8 aF[4];                                                               \
      _Pragma("unroll") for (int m = 0; m < 4; ++m) aF[m] =                    \
          *(const sx8*)&Ash[buf][ao[m]];                                       \
      sx8 bg = *(const sx8*)&Bsh[buf][bGo];                                    \
      sx8 bl = *(const sx8*)&Bsh[buf][bLo];                                    \
      _Pragma("unroll") for (int m = 0; m < 4; ++m) {                          \
        accG[m] = MFMA16(aF[m], bg, accG[m]);                                  \
        accL[m] = MFMA16(aF[m], bl, accL[m]);                                  \
      }                                                                        \
    }

  G1_STAGE(0, 0);
  int buf = 0;
  for (int t = 0; t < NSTEP; ++t) {
    __syncthreads();
    G1_STAGE(buf ^ 1, t + 1);
    G1_COMP(buf);
    buf ^= 1;
  }

  const int col = c0 + wn * 16 + fr;
  const float bg = b_gate_up[e * (2 * IDIM) + col];
  const float bl = b_gate_up[e * (2 * IDIM) + IDIM + col];
  #pragma unroll
  for (int m = 0; m < 4; ++m) {
    #pragma unroll
    for (int r = 0; r < 4; ++r) {
      int slot = m0 + wm * 64 + m * 16 + fq * 4 + r;
      if (slot < ce) {
        float g = accG[m][r] + bg;
        float l = accL[m][r] + bl;
        float a = g * (1.0f / (1.0f + __expf(-1.702f * g))) * (l + 1.0f);
        act_bf[((size_t)e * NTOK + slot) * IDIM + col] = f2bf(a);
      }
    }
  }
}

// GEMM2: BM=128 x 64, BK=32, 4 waves (2m x 2n), dbuf 24KB LDS, 5 blocks/CU.
__global__ __launch_bounds__(256, 5) void gemm2_k(
    const unsigned short* __restrict__ act_bf, const float* __restrict__ w_down,
    const float* __restrict__ b_down, const int* __restrict__ cnt,
    const int* __restrict__ tok, const float* __restrict__ wgt,
    float* __restrict__ out) {
  const int h = blockIdx.x;
  const int zl = (h >> 3) & 7;
  const int u = ((h >> 6) << 3) | (h & 7);  // u in [0,360)
  const int e = u / 45;
  const int c0 = (u % 45) * 64;
  const int m0 = zl * 128;
  const int ce = cnt[e];
  if (m0 >= ce) return;

  const int tid = threadIdx.x, lane = tid & 63, wid = tid >> 6;
  const int fr = lane & 15, fq = lane >> 4;
  const int wm = wid >> 1, wn = wid & 1;

  __shared__ __align__(16) unsigned short Ash[2][128 * BK];
  __shared__ __align__(16) unsigned short Bsh[2][64 * BK];

  const fx4 FZ = {0.f, 0.f, 0.f, 0.f};
  fx4 acc[4][2];
  #pragma unroll
  for (int m = 0; m < 4; m++)
    #pragma unroll
    for (int n = 0; n < 2; n++) acc[m][n] = FZ;

  const int srcc = ((lane & 3) ^ ((lane >> 2) & 3) ^ ((lane >> 4) & 3)) * 8;
  const unsigned short* gA[2];
  #pragma unroll
  for (int j = 0; j < 2; ++j) {
    int R = m0 + wid * 32 + j * 16 + (lane >> 2);  // < 1024 always
    gA[j] = act_bf + ((size_t)e * NTOK + R) * IDIM + srcc;
  }
  const int br = tid >> 2, bs = tid & 3;
  const float* srcB = w_down + (size_t)e * HDIM * IDIM +
                      (size_t)(c0 + br) * IDIM + bs * 8;
  const int bwo = br * BK + ((bs ^ (br & 3) ^ ((br >> 2) & 3)) * 8);

  const int rdc = (fq ^ (fr & 3) ^ ((fr >> 2) & 3)) * 8;
  int ao[4];
  #pragma unroll
  for (int m = 0; m < 4; m++) ao[m] = (wm * 64 + m * 16 + fr) * BK + rdc;
  int bo[2];
  #pragma unroll
  for (int n = 0; n < 2; n++) bo[n] = (wn * 32 + n * 16 + fr) * BK + rdc;

  #define G2_STAGE(buf, kt)                                                    \
    {                                                                          \
      const int ko = ((kt) < NSTEP ? (kt) : 0) * BK;                           \
      __builtin_amdgcn_global_load_lds((gas_p)(gA[0] + ko),                    \
                                       (las_p)&Ash[buf][(wid * 32) * BK], 16,  \
                                       0, 0);                                  \
      __builtin_amdgcn_global_load_lds(                                        \
          (gas_p)(gA[1] + ko), (las_p)&Ash[buf][(wid * 32 + 16) * BK], 16, 0,  \
          0);                                                                  \
      fx4 v0 = *(const fx4*)(srcB + ko);                                       \
      fx4 v1 = *(const fx4*)(srcB + ko + 4);                                   \
      *(usx8*)&Bsh[buf][bwo] = cvt8(v0, v1);                                   \
    }
  #define G2_COMP(buf)                                                         \
    {                                                                          \
      sx8 aF[4];                                                               \
      _Pragma("unroll") for (int m = 0; m < 4; ++m) aF[m] =                    \
          *(const sx8*)&Ash[buf][ao[m]];                                       \
      sx8 b0 = *(const sx8*)&Bsh[buf][bo[0]];                                  \
      sx8 b1 = *(const sx8*)&Bsh[buf][bo[1]];                                  \
      _Pragma("unroll") for (int m = 0; m < 4; ++m) {                          \
        acc[m][0] = MFMA16(aF[m], b0, acc[m][0]);                              \
        acc[m][1] = MFMA16(aF[m], b1, acc[m][1]);                              \
      }                                                                        \
    }

  G2_STAGE(0, 0);
  int buf = 0;
  for (int t = 0; t < NSTEP; ++t) {
    __syncthreads();
    G2_STAGE(buf ^ 1, t + 1);
    G2_COMP(buf);
    buf ^= 1;
  }

  #pragma unroll
  for (int n = 0; n < 2; ++n) {
    const int col = c0 + wn * 32 + n * 16 + fr;
    const float bias = b_down[e * HDIM + col];
    #pragma unroll
    for (int m = 0; m < 4; ++m) {
      #pragma unroll
      for (int r = 0; r < 4; ++r) {
        int slot = m0 + wm * 64 + m * 16 + fq * 4 + r;
        if (slot < ce) {
          int token = tok[e * NTOK + slot];
          float w = wgt[e * NTOK + slot];
          atomicAdd(&out[(size_t)token * HDIM + col], w * (acc[m][n][r] + bias));
        }
      }
    }
  }
}

extern "C" void kernel_launch(void* const* d_in, const int* in_sizes, int n_in,
                              void* d_out, int out_size, void* d_ws,
                              size_t ws_size, hipStream_t stream) {
  const float* x = (const float*)d_in[0];
  const float* norm_w = (const float*)d_in[1];
  const float* gate_w = (const float*)d_in[2];
  const float* gate_b = (const float*)d_in[3];
  const float* w_gate_up = (const float*)d_in[4];
  const float* b_gate_up = (const float*)d_in[5];
  const float* w_down = (const float*)d_in[6];
  const float* b_down = (const float*)d_in[7];
  float* out = (float*)d_out;

  char* ws = (char*)d_ws;
  unsigned short* t_bf = (unsigned short*)ws;
  ws += (size_t)NTOK * HDIM * 2;
  unsigned short* act_bf = (unsigned short*)ws;
  ws += (size_t)NEXP * NTOK * IDIM * 2;
  int* cnt = (int*)ws;
  ws += 256;
  int* tok = (int*)ws;
  ws += (size_t)NEXP * NTOK * 4;
  float* wgt = (float*)ws;
  ws += (size_t)NEXP * NTOK * 4;

  hipMemsetAsync(cnt, 0, NEXP * sizeof(int), stream);
  init_out_k<<<2880, 256, 0, stream>>>(x, out);
  rms_router_k<<<NTOK, 256, 0, stream>>>(x, norm_w, gate_w, gate_b, t_bf, cnt,
                                         tok, wgt);
  // 1D grids; in-kernel decode puts the 8 row-tile twins of each
  // (expert, col-slice) on the SAME XCD within a 56-block dispatch window.
  gemm1_k<<<8 * 90 * 8, 256, 0, stream>>>(t_bf, w_gate_up, b_gate_up, cnt, tok,
                                          act_bf);
  gemm2_k<<<8 * 45 * 8, 256, 0, stream>>>(act_bf, w_down, b_down, cnt, tok,
                                          wgt, out);
}